// Round 4
// baseline (457.514 us; speedup 1.0000x reference)
//
#include <hip/hip_runtime.h>

typedef unsigned short u16;
typedef unsigned int u32;
typedef __attribute__((ext_vector_type(8))) short short8;
typedef __attribute__((ext_vector_type(4))) float floatx4;

__device__ inline float bf2f(u16 h) {
  union { u32 u; float f; } v; v.u = ((u32)h) << 16; return v.f;
}
__device__ inline u16 f2bf(float f) {
  union { float f; u32 u; } v; v.f = f;
  u32 u = v.u;
  return (u16)((u + 0x7fffu + ((u >> 16) & 1u)) >> 16);
}
// dtype-generic load: isbf is wave-uniform (from sniffer flag)
__device__ inline float ldf(const void* p, int i, int isbf) {
  return isbf ? bf2f(((const u16*)p)[i]) : ((const float*)p)[i];
}

// ---------------- K0: input dtype sniffer ----------------
// Sample 256 u32 words of `weight` (pristine N(0,1)). If the data is bf16, the
// low u16 of each word is a bf16 with exponent ~126 (in [96,160] w.p. ~1). If
// f32, those bits are uniform mantissa bits (in-band w.p. ~0.25).
__global__ void sniff_kernel(const u32* __restrict__ w, int* __restrict__ flag) {
  __shared__ int cnt;
  if (threadIdx.x == 0) cnt = 0;
  __syncthreads();
  int c = 0;
  #pragma unroll
  for (int i = 0; i < 4; ++i) {
    u32 v = w[1024 + threadIdx.x * 4 + i];
    int e = (v >> 7) & 0xFF;          // exponent field of the low u16 as bf16
    if (e >= 96 && e <= 160) c++;
  }
  atomicAdd(&cnt, c);
  __syncthreads();
  if (threadIdx.x == 0) *flag = (cnt >= 154) ? 1 : 0;   // 60% of 256
}

// ---------------- K1: style linears (s[8,512], cw[35,512], cb[35,512]) ----------------
__global__ void styles_kernel(const void* __restrict__ style, const void* __restrict__ class_style,
                              const void* __restrict__ mod_w, const void* __restrict__ mod_b,
                              const void* __restrict__ cw_w, const void* __restrict__ cw_b,
                              const void* __restrict__ cb_w, const void* __restrict__ cb_b,
                              const int* __restrict__ flagp,
                              float* __restrict__ s, float* __restrict__ cw, float* __restrict__ cb) {
  const int isbf = *flagp;
  int row = blockIdx.x;  // 0..77
  const void *vec, *wm, *bias; float* out; int voff;
  if (row < 8)        { vec = style;       voff = row*512;        wm = mod_w; bias = mod_b; out = s  + row*512; }
  else if (row < 43)  { vec = class_style; voff = (row-8)*512;    wm = cw_w;  bias = cw_b;  out = cw + (row-8)*512; }
  else                { vec = class_style; voff = (row-43)*512;   wm = cb_w;  bias = cb_b;  out = cb + (row-43)*512; }
  __shared__ float v[512];
  for (int i = threadIdx.x; i < 512; i += 256) v[i] = ldf(vec, voff + i, isbf);
  __syncthreads();
  const float inv = 0.04419417382415922f;  // 1/sqrt(512)
  for (int o = threadIdx.x; o < 512; o += 256) {
    float acc = 0.f;
    for (int k = 0; k < 512; ++k)
      acc += ldf(wm, o*512 + k, isbf) * v[k];
    out[o] = acc * inv + ldf(bias, o, isbf);
  }
}

// ---------------- K2: weight transpose wT[tap][cout][cin] + wsq[cout][cin] ----------------
__global__ void wprep_kernel(const void* __restrict__ weight, const int* __restrict__ flagp,
                             u16* __restrict__ wT, float* __restrict__ wsq) {
  const int isbf = *flagp;
  const int co = blockIdx.x;
  for (int ci = threadIdx.x; ci < 512; ci += 256) {
    float sq = 0.f;
    #pragma unroll
    for (int tap = 0; tap < 9; ++tap) {
      float fv = ldf(weight, ((co*512) + ci)*9 + tap, isbf);
      sq += fv*fv;
      wT[((tap*512) + co)*512 + ci] = f2bf(fv);
    }
    wsq[co*512 + ci] = sq;
  }
}

// ---------------- K3: x transpose+modulate: xT[b][h][w][ci] = x[b][ci][h][w]*s[b][ci] ----------------
__global__ void xtrans_kernel(const void* __restrict__ x, const float* __restrict__ s,
                              const int* __restrict__ flagp, u16* __restrict__ xT) {
  const int isbf = *flagp;
  const int t = threadIdx.x;
  const int w = t & 63, cq = t >> 6;
  const int b = blockIdx.z, h = blockIdx.y;
  const int ci0 = blockIdx.x*32 + cq*8;
  float f[8];
  #pragma unroll
  for (int j = 0; j < 8; ++j) {
    float xv = ldf(x, (((b*512) + ci0 + j)*64 + h)*64 + w, isbf);
    f[j] = xv * s[b*512 + ci0 + j];
  }
  u32 outp[4];
  #pragma unroll
  for (int i = 0; i < 4; ++i)
    outp[i] = (u32)f2bf(f[2*i]) | ((u32)f2bf(f[2*i+1]) << 16);
  uint4 po = {outp[0], outp[1], outp[2], outp[3]};
  *(uint4*)&xT[(size_t)(((b*64) + h)*64 + w)*512 + ci0] = po;
}

// ---------------- K4: MFMA conv. block: 64 couts x (4 rows x 64 w). y(f32) -> d_out ----------------
__global__ __launch_bounds__(256, 2) void conv_kernel(const u16* __restrict__ xT, const u16* __restrict__ wT,
                                                      float* __restrict__ y) {
  __shared__ __align__(16) u16 xs[6*66*32];   // [dr][c][ci] 12672 elems = 25344 B
  __shared__ __align__(16) u16 wsm[576*32];   // [tap*64+cout][ci] 18432 elems = 36864 B
  const int tid = threadIdx.x;
  const int lane = tid & 63;
  const int wid = tid >> 6;
  const int ct0 = blockIdx.x * 64;
  const int h0 = blockIdx.y * 4;
  const int b  = blockIdx.z;

  // zero column-halo cells (c==0, c==65) once; row halos zero-filled each chunk by staging
  for (int idx = tid; idx < 6*66; idx += 256) {
    int dr = idx / 66, c = idx - dr*66;
    if (c == 0 || c == 65) {
      uint4 z = {0,0,0,0};
      uint4* p = (uint4*)&xs[idx*32];
      p[0] = z; p[1] = z; p[2] = z; p[3] = z;
    }
  }

  floatx4 acc[4][4];
  #pragma unroll
  for (int i = 0; i < 4; ++i) {
    #pragma unroll
    for (int j = 0; j < 4; ++j) acc[i][j] = (floatx4)(0.f);
  }

  const int m = lane & 15, qd = lane >> 4;    // mfma fragment indices

  for (int chunk = 0; chunk < 16; ++chunk) {
    const int ci0 = chunk * 32;
    __syncthreads();  // prev chunk's MFMA reads done (and halo zeros ordered, 1st iter)

    // stage x: 1536 16B-chunks, 6 per thread
    #pragma unroll
    for (int j = 0; j < 6; ++j) {
      int g16 = tid + j*256;                  // 0..1535
      int q = g16 & 3, cell = g16 >> 2;       // cell 0..383
      int dr = cell >> 6, c64 = cell & 63;
      int hin = h0 + dr - 1;
      uint4 v = {0,0,0,0};
      if (hin >= 0 && hin <= 63)
        v = *(const uint4*)&xT[(size_t)(((b*64 + hin)*64) + c64)*512 + ci0 + q*8];
      *(uint4*)&xs[(dr*66 + 1 + c64)*32 + q*8] = v;
    }
    // stage w: 2304 16B-chunks, 9 per thread
    #pragma unroll
    for (int j = 0; j < 9; ++j) {
      int g16 = tid + j*256;                  // 0..2303
      int q = g16 & 3, cell = g16 >> 2;       // cell 0..575 = tap*64+cout_local
      int tap = cell >> 6, co = cell & 63;
      uint4 v = *(const uint4*)&wT[(size_t)((tap*512) + ct0 + co)*512 + ci0 + q*8];
      *(uint4*)&wsm[cell*32 + q*8] = v;
    }
    __syncthreads();

    #pragma unroll
    for (int tap = 0; tap < 9; ++tap) {
      const int k1 = tap / 3, k2 = tap - k1*3;
      short8 af[4], bfr[4];
      #pragma unroll
      for (int mi = 0; mi < 4; ++mi)
        af[mi] = *(const short8*)&wsm[((tap*64) + mi*16 + m)*32 + qd*8];
      const int drr = wid + k1;
      #pragma unroll
      for (int ni = 0; ni < 4; ++ni)
        bfr[ni] = *(const short8*)&xs[(drr*66 + ni*16 + m + k2)*32 + qd*8];
      #pragma unroll
      for (int ni = 0; ni < 4; ++ni) {
        #pragma unroll
        for (int mi = 0; mi < 4; ++mi)
          acc[mi][ni] = __builtin_amdgcn_mfma_f32_16x16x32_bf16(af[mi], bfr[ni], acc[mi][ni], 0, 0, 0);
      }
    }
  }

  // write y (pre-norm conv result, f32) into d_out
  const int h = h0 + wid;
  #pragma unroll
  for (int mi = 0; mi < 4; ++mi) {
    #pragma unroll
    for (int ni = 0; ni < 4; ++ni) {
      #pragma unroll
      for (int r = 0; r < 4; ++r) {
        int co = ct0 + mi*16 + qd*4 + r;      // C/D layout: row=(lane>>4)*4+reg, col=lane&15
        int w = ni*16 + m;
        y[(size_t)(((b*512) + co)*64 + h)*64 + w] = acc[mi][ni][r];
      }
    }
  }
}

// ---------------- K5: per-(b,cout) stats: mu, istd = rsqrt(var + 1e-5*SS + 4.608e-10) ----------------
__global__ void stats_kernel(const float* __restrict__ y, const float* __restrict__ s,
                             const float* __restrict__ wsq, float* __restrict__ mu, float* __restrict__ istd) {
  const int bc = blockIdx.x;          // b*512+cout
  const int b = bc >> 9, co = bc & 511;
  const int t = threadIdx.x;
  const float4* yp = (const float4*)(y + (size_t)bc*4096 + t*16);
  float sum = 0.f, sq = 0.f;
  #pragma unroll
  for (int i = 0; i < 4; ++i) {
    float4 p = yp[i];
    sum += p.x + p.y + p.z + p.w;
    sq  += p.x*p.x + p.y*p.y + p.z*p.z + p.w*p.w;
  }
  float ssp = 0.f;
  #pragma unroll
  for (int rep = 0; rep < 2; ++rep) {
    int ci = t + rep*256;
    float sv = s[b*512 + ci];
    ssp += sv*sv*wsq[co*512 + ci];
  }
  #pragma unroll
  for (int off = 32; off > 0; off >>= 1) {
    sum += __shfl_down(sum, off, 64);
    sq  += __shfl_down(sq, off, 64);
    ssp += __shfl_down(ssp, off, 64);
  }
  __shared__ float red[12];
  int lane = t & 63, wv = t >> 6;
  if (lane == 0) { red[wv] = sum; red[4+wv] = sq; red[8+wv] = ssp; }
  __syncthreads();
  if (t == 0) {
    float S  = red[0]+red[1]+red[2]+red[3];
    float Q  = red[4]+red[5]+red[6]+red[7];
    float SS = red[8]+red[9]+red[10]+red[11];
    float mval = S * (1.f/4096.f);
    float var = fmaxf(Q * (1.f/4096.f) - mval*mval, 0.f);   // guard fp32 cancellation
    float eps = 1e-5f*SS + 4.608e-10f;    // = eps_in/(scale*demod)^2, exact
    mu[bc] = mval;
    istd[bc] = rsqrtf(var + eps);
  }
}

// ---------------- K6: normalize + CLADE (in place on d_out, f32) ----------------
__global__ void epi_kernel(float* __restrict__ y, const float* __restrict__ mu, const float* __restrict__ istd,
                           const float* __restrict__ cw, const float* __restrict__ cb,
                           const int* __restrict__ label) {
  __shared__ float2 tab[35];
  const int blk = blockIdx.x;          // 8192 = 4096 planes x 2 halves
  const int bc = blk >> 1, half = blk & 1;
  const int b = bc >> 9, co = bc & 511;
  const int t = threadIdx.x;
  if (t < 35) tab[t] = make_float2(cw[t*512 + co], cb[t*512 + co]);
  __syncthreads();
  const float mval = mu[bc], is = istd[bc];
  const int base = half*2048 + t*8;
  const int h = base >> 6, w = base & 63;
  float* yp = y + (size_t)bc*4096 + base;
  float4 v0 = *(const float4*)yp;
  float4 v1 = *(const float4*)(yp + 4);
  const int* lp = label + ((b*64) + h)*64 + w;
  float vin[8] = {v0.x, v0.y, v0.z, v0.w, v1.x, v1.y, v1.z, v1.w};
  float vout[8];
  #pragma unroll
  for (int i = 0; i < 8; ++i) {
    float a = (vin[i] - mval) * is;
    float2 wb = tab[lp[i]];
    vout[i] = a*wb.x + wb.y;
  }
  float4 o0 = {vout[0], vout[1], vout[2], vout[3]};
  float4 o1 = {vout[4], vout[5], vout[6], vout[7]};
  *(float4*)yp = o0;
  *(float4*)(yp + 4) = o1;
}

extern "C" void kernel_launch(void* const* d_in, const int* in_sizes, int n_in,
                              void* d_out, int out_size, void* d_ws, size_t ws_size,
                              hipStream_t stream) {
  (void)in_sizes; (void)n_in; (void)out_size; (void)ws_size;
  const void* input       = d_in[0];
  const void* style       = d_in[1];
  const void* class_style = d_in[2];
  const void* weight      = d_in[3];
  const void* mod_w       = d_in[4];
  const void* mod_b       = d_in[5];
  const void* cw_w        = d_in[6];
  const void* cw_b        = d_in[7];
  const void* cb_w        = d_in[8];
  const void* cb_b        = d_in[9];
  const int* label        = (const int*)d_in[10];
  float* y = (float*)d_out;                   // f32 conv result in d_out, normalized in place

  char* ws = (char*)d_ws;
  u16*   xT   = (u16*)  (ws + 0);             // 33,554,432 B  [b][h][w][ci] bf16
  u16*   wT   = (u16*)  (ws + 33554432);      //  4,718,592 B  [tap][cout][ci] bf16
  float* wsq  = (float*)(ws + 38273024);      //  1,048,576 B  [cout][ci]
  float* s    = (float*)(ws + 39321600);      //     16,384 B  [b][ci]
  float* cw   = (float*)(ws + 39337984);      //     71,680 B  [ncls][cout]
  float* cb   = (float*)(ws + 39409664);      //     71,680 B
  float* mu   = (float*)(ws + 39481344);      //     16,384 B
  float* istd = (float*)(ws + 39497728);      //     16,384 B
  int*   flag = (int*)  (ws + 39514112);      //          4 B  (total 39,514,116 B)

  hipLaunchKernelGGL(sniff_kernel, dim3(1), dim3(64), 0, stream, (const u32*)weight, flag);
  hipLaunchKernelGGL(styles_kernel, dim3(78), dim3(256), 0, stream,
                     style, class_style, mod_w, mod_b, cw_w, cw_b, cb_w, cb_b,
                     (const int*)flag, s, cw, cb);
  hipLaunchKernelGGL(wprep_kernel, dim3(512), dim3(256), 0, stream, weight, (const int*)flag, wT, wsq);
  hipLaunchKernelGGL(xtrans_kernel, dim3(16, 64, 8), dim3(256), 0, stream, input, s, (const int*)flag, xT);
  hipLaunchKernelGGL(conv_kernel, dim3(8, 16, 8), dim3(256), 0, stream, xT, wT, y);
  hipLaunchKernelGGL(stats_kernel, dim3(4096), dim3(256), 0, stream, y, s, wsq, mu, istd);
  hipLaunchKernelGGL(epi_kernel, dim3(8192), dim3(256), 0, stream, y, mu, istd, cw, cb, label);
}

// Round 6
// 397.959 us; speedup vs baseline: 1.1497x; 1.1497x over previous
//
#include <hip/hip_runtime.h>

typedef unsigned short u16;
typedef unsigned int u32;
typedef __attribute__((ext_vector_type(8))) short short8;
typedef __attribute__((ext_vector_type(4))) float floatx4;

__device__ inline float bf2f(u16 h) {
  union { u32 u; float f; } v; v.u = ((u32)h) << 16; return v.f;
}
__device__ inline u16 f2bf(float f) {
  union { float f; u32 u; } v; v.f = f;
  u32 u = v.u;
  return (u16)((u + 0x7fffu + ((u >> 16) & 1u)) >> 16);
}
// dtype-generic load: isbf is wave-uniform (from sniffer flag)
__device__ inline float ldf(const void* p, int i, int isbf) {
  return isbf ? bf2f(((const u16*)p)[i]) : ((const float*)p)[i];
}

// ---------------- K0: input dtype sniffer ----------------
__global__ void sniff_kernel(const u32* __restrict__ w, int* __restrict__ flag) {
  __shared__ int cnt;
  if (threadIdx.x == 0) cnt = 0;
  __syncthreads();
  int c = 0;
  #pragma unroll
  for (int i = 0; i < 4; ++i) {
    u32 v = w[1024 + threadIdx.x * 4 + i];
    int e = (v >> 7) & 0xFF;          // exponent field of the low u16 as bf16
    if (e >= 96 && e <= 160) c++;
  }
  atomicAdd(&cnt, c);
  __syncthreads();
  if (threadIdx.x == 0) *flag = (cnt >= 154) ? 1 : 0;   // 60% of 256
}

// ---------------- K1: style linears (s[8,512], cw[35,512], cb[35,512]) ----------------
__global__ void styles_kernel(const void* __restrict__ style, const void* __restrict__ class_style,
                              const void* __restrict__ mod_w, const void* __restrict__ mod_b,
                              const void* __restrict__ cw_w, const void* __restrict__ cw_b,
                              const void* __restrict__ cb_w, const void* __restrict__ cb_b,
                              const int* __restrict__ flagp,
                              float* __restrict__ s, float* __restrict__ cw, float* __restrict__ cb) {
  const int isbf = *flagp;
  int row = blockIdx.x;  // 0..77
  const void *vec, *wm, *bias; float* out; int voff;
  if (row < 8)        { vec = style;       voff = row*512;        wm = mod_w; bias = mod_b; out = s  + row*512; }
  else if (row < 43)  { vec = class_style; voff = (row-8)*512;    wm = cw_w;  bias = cw_b;  out = cw + (row-8)*512; }
  else                { vec = class_style; voff = (row-43)*512;   wm = cb_w;  bias = cb_b;  out = cb + (row-43)*512; }
  __shared__ float v[512];
  for (int i = threadIdx.x; i < 512; i += 256) v[i] = ldf(vec, voff + i, isbf);
  __syncthreads();
  const float inv = 0.04419417382415922f;  // 1/sqrt(512)
  for (int o = threadIdx.x; o < 512; o += 256) {
    float acc = 0.f;
    if (isbf) {
      for (int k = 0; k < 512; ++k) acc += bf2f(((const u16*)wm)[o*512 + k]) * v[k];
    } else {
      const float4* wr = (const float4*)((const float*)wm + o*512);
      for (int k = 0; k < 128; ++k) {
        float4 p = wr[k];
        acc += p.x*v[k*4+0] + p.y*v[k*4+1] + p.z*v[k*4+2] + p.w*v[k*4+3];
      }
    }
    out[o] = acc * inv + ldf(bias, o, isbf);
  }
}

// ---------------- K2: weight transpose wT[tap][cout][cin] + wsqT[cin][cout] ----------------
__global__ void wprep_kernel(const void* __restrict__ weight, const int* __restrict__ flagp,
                             u16* __restrict__ wT, float* __restrict__ wsqT) {
  const int isbf = *flagp;
  const int co = blockIdx.x;
  __shared__ float wsmem[4608];
  for (int i = threadIdx.x; i < 4608; i += 256)
    wsmem[i] = ldf(weight, co*4608 + i, isbf);   // coalesced
  __syncthreads();
  for (int ci = threadIdx.x; ci < 512; ci += 256) {
    float sq = 0.f;
    #pragma unroll
    for (int tap = 0; tap < 9; ++tap) {
      float fv = wsmem[ci*9 + tap];
      sq += fv*fv;
      wT[((tap*512) + co)*512 + ci] = f2bf(fv);
    }
    wsqT[ci*512 + co] = sq;
  }
}

// ---------------- K3: x transpose+modulate: xT[b][h][w][ci] = x[b][ci][h][w]*s[b][ci] ----------------
__global__ void xtrans_kernel(const void* __restrict__ x, const float* __restrict__ s,
                              const int* __restrict__ flagp, u16* __restrict__ xT) {
  const int isbf = *flagp;
  const int t = threadIdx.x;
  const int w = t & 63, cq = t >> 6;
  const int b = blockIdx.z, h = blockIdx.y;
  const int ci0 = blockIdx.x*32 + cq*8;
  float f[8];
  #pragma unroll
  for (int j = 0; j < 8; ++j) {
    float xv = ldf(x, (((b*512) + ci0 + j)*64 + h)*64 + w, isbf);
    f[j] = xv * s[b*512 + ci0 + j];
  }
  u32 outp[4];
  #pragma unroll
  for (int i = 0; i < 4; ++i)
    outp[i] = (u32)f2bf(f[2*i]) | ((u32)f2bf(f[2*i+1]) << 16);
  uint4 po = {outp[0], outp[1], outp[2], outp[3]};
  *(uint4*)&xT[(size_t)(((b*64) + h)*64 + w)*512 + ci0] = po;
}

// ---------------- K4: MFMA conv + fused IN partial sums ----------------
// LDS layouts are phase-contiguous: every 16-lane group of a ds_read_b128
// covers a contiguous (or XOR-permuted-within) 256B run -> <=2-way banks.
//   xs : [q][dr][c]   q=ci/8 (0..3), dr 0..5, c 0..65; 16B cells; 25344 B
//   wsm: [tap][q][co^ (q<<2)]                           16B cells; 36864 B
__global__ __launch_bounds__(256, 2) void conv_kernel(const u16* __restrict__ xT, const u16* __restrict__ wT,
                                                      float* __restrict__ y, float* __restrict__ part) {
  __shared__ __align__(16) u16 xs[4*6*66*8];   // 12672 shorts = 25344 B
  __shared__ __align__(16) u16 wsm[9*4*64*8];  // 18432 shorts = 36864 B
  const int tid = threadIdx.x;
  const int lane = tid & 63;
  const int wid = tid >> 6;
  const int ct0 = blockIdx.x * 64;
  const int h0 = blockIdx.y * 4;
  const int b  = blockIdx.z;

  // zero column-halo cells (c==0, c==65) for ALL q in 0..3, dr in 0..5
  // (R5 bug: tid<48 covered only q=0..2 -> q=3 halos were uninitialized LDS -> NaN)
  if (tid < 64) {
    int q = tid >> 4, rem = tid & 15;          // q 0..3; rem = dr*2+side, need rem<12
    if (rem < 12) {
      int dr = rem >> 1, side = rem & 1;
      uint4 z = {0,0,0,0};
      *(uint4*)&xs[(((q*6 + dr)*66) + side*65)*8] = z;
    }
  }

  floatx4 acc[4][4];
  #pragma unroll
  for (int i = 0; i < 4; ++i) {
    #pragma unroll
    for (int j = 0; j < 4; ++j) acc[i][j] = (floatx4)(0.f);
  }

  const int m = lane & 15, qd = lane >> 4;     // mfma fragment indices

  for (int chunk = 0; chunk < 16; ++chunk) {
    const int ci0 = chunk * 32;
    __syncthreads();  // prev chunk's MFMA reads done (and halo zeros, 1st iter)

    // stage x: 1536 16B-chunks, 6 per thread
    #pragma unroll
    for (int j = 0; j < 6; ++j) {
      int g16 = tid + j*256;                   // 0..1535
      int q = g16 & 3, cell = g16 >> 2;        // cell 0..383
      int dr = cell >> 6, c64 = cell & 63;
      int hin = h0 + dr - 1;
      uint4 v = {0,0,0,0};
      if (hin >= 0 && hin <= 63)
        v = *(const uint4*)&xT[(size_t)(((b*64 + hin)*64) + c64)*512 + ci0 + q*8];
      *(uint4*)&xs[(((q*6 + dr)*66) + 1 + c64)*8] = v;
    }
    // stage w: 2304 16B-chunks, 9 per thread (co XOR-swizzled by q)
    #pragma unroll
    for (int j = 0; j < 9; ++j) {
      int g16 = tid + j*256;                   // 0..2303
      int q = g16 & 3, cell = g16 >> 2;        // cell 0..575 = tap*64+co
      int tap = cell >> 6, co = cell & 63;
      uint4 v = *(const uint4*)&wT[(size_t)((tap*512) + ct0 + co)*512 + ci0 + q*8];
      *(uint4*)&wsm[(((tap*4 + q)*64) + (co ^ (q << 2)))*8] = v;
    }
    __syncthreads();

    #pragma unroll
    for (int tap = 0; tap < 9; ++tap) {
      const int k1 = tap / 3, k2 = tap - k1*3;
      short8 af[4], bfr[4];
      #pragma unroll
      for (int mi = 0; mi < 4; ++mi)
        af[mi] = *(const short8*)&wsm[(((tap*4 + qd)*64) + ((mi*16 + m) ^ (qd << 2)))*8];
      const int drr = wid + k1;
      #pragma unroll
      for (int ni = 0; ni < 4; ++ni)
        bfr[ni] = *(const short8*)&xs[(((qd*6 + drr)*66) + ni*16 + m + k2)*8];
      #pragma unroll
      for (int ni = 0; ni < 4; ++ni) {
        #pragma unroll
        for (int mi = 0; mi < 4; ++mi)
          acc[mi][ni] = __builtin_amdgcn_mfma_f32_16x16x32_bf16(af[mi], bfr[ni], acc[mi][ni], 0, 0, 0);
      }
    }
  }

  // write y (pre-norm conv result, f32) into d_out
  const int h = h0 + wid;
  #pragma unroll
  for (int mi = 0; mi < 4; ++mi) {
    #pragma unroll
    for (int ni = 0; ni < 4; ++ni) {
      #pragma unroll
      for (int r = 0; r < 4; ++r) {
        int co = ct0 + mi*16 + qd*4 + r;       // C/D: row=(lane>>4)*4+reg, col=lane&15
        int w = ni*16 + m;
        y[(size_t)(((b*512) + co)*64 + h)*64 + w] = acc[mi][ni][r];
      }
    }
  }

  // fused IN partials: per-cout sum / sumsq over this block's 4x64 tile
  float s1[16], s2[16];
  #pragma unroll
  for (int mi = 0; mi < 4; ++mi) {
    #pragma unroll
    for (int r = 0; r < 4; ++r) {
      float a0 = acc[mi][0][r], a1 = acc[mi][1][r], a2 = acc[mi][2][r], a3 = acc[mi][3][r];
      s1[mi*4+r] = (a0+a1) + (a2+a3);
      s2[mi*4+r] = (a0*a0+a1*a1) + (a2*a2+a3*a3);
    }
  }
  #pragma unroll
  for (int off = 1; off < 16; off <<= 1) {
    #pragma unroll
    for (int i = 0; i < 16; ++i) {
      s1[i] += __shfl_xor(s1[i], off, 64);
      s2[i] += __shfl_xor(s2[i], off, 64);
    }
  }
  __syncthreads();                 // all waves done reading xs for MFMA
  float* red = (float*)xs;         // reuse LDS: [wid][co][2] = 512 floats
  if (m == 0) {
    #pragma unroll
    for (int mi = 0; mi < 4; ++mi) {
      #pragma unroll
      for (int r = 0; r < 4; ++r) {
        int co = mi*16 + qd*4 + r;
        red[(wid*64 + co)*2 + 0] = s1[mi*4+r];
        red[(wid*64 + co)*2 + 1] = s2[mi*4+r];
      }
    }
  }
  __syncthreads();
  if (tid < 128) {
    int co = tid >> 1, which = tid & 1;
    float v = (red[(0*64+co)*2+which] + red[(1*64+co)*2+which])
            + (red[(2*64+co)*2+which] + red[(3*64+co)*2+which]);
    part[(size_t)(((b*16 + blockIdx.y)*512) + ct0 + co)*2 + which] = v;
  }
}

// ---------------- K5: finalize mu/istd from partials + SS-eps term ----------------
__global__ void finalize_kernel(const float* __restrict__ part, const float* __restrict__ s,
                                const float* __restrict__ wsqT,
                                float* __restrict__ mu, float* __restrict__ istd) {
  const int gid = blockIdx.x*256 + threadIdx.x;   // 0..4095 = b*512+co
  const int b = gid >> 9, co = gid & 511;
  float S = 0.f, Q = 0.f;
  #pragma unroll
  for (int hb = 0; hb < 16; ++hb) {
    S += part[(size_t)(((b*16 + hb)*512) + co)*2 + 0];
    Q += part[(size_t)(((b*16 + hb)*512) + co)*2 + 1];
  }
  float SS = 0.f;
  for (int ci = 0; ci < 512; ++ci) {
    float sv = s[b*512 + ci];
    SS += sv*sv * wsqT[ci*512 + co];   // coalesced across threads
  }
  float mval = S * (1.f/4096.f);
  float var = fmaxf(Q * (1.f/4096.f) - mval*mval, 0.f);
  float eps = 1e-5f*SS + 4.608e-10f;   // = eps_in/(scale*demod)^2, exact
  mu[gid] = mval;
  istd[gid] = rsqrtf(var + eps);
}

// ---------------- K6: normalize + CLADE (in place on d_out, f32) ----------------
__global__ void epi_kernel(float* __restrict__ y, const float* __restrict__ mu, const float* __restrict__ istd,
                           const float* __restrict__ cw, const float* __restrict__ cb,
                           const int* __restrict__ label) {
  __shared__ float2 tab[35];
  const int blk = blockIdx.x;          // 8192 = 4096 planes x 2 halves
  const int bc = blk >> 1, half = blk & 1;
  const int b = bc >> 9, co = bc & 511;
  const int t = threadIdx.x;
  if (t < 35) tab[t] = make_float2(cw[t*512 + co], cb[t*512 + co]);
  __syncthreads();
  const float mval = mu[bc], is = istd[bc];
  const int base = half*2048 + t*8;
  const int h = base >> 6, w = base & 63;
  float* yp = y + (size_t)bc*4096 + base;
  float4 v0 = *(const float4*)yp;
  float4 v1 = *(const float4*)(yp + 4);
  const int* lp = label + ((b*64) + h)*64 + w;
  float vin[8] = {v0.x, v0.y, v0.z, v0.w, v1.x, v1.y, v1.z, v1.w};
  float vout[8];
  #pragma unroll
  for (int i = 0; i < 8; ++i) {
    float a = (vin[i] - mval) * is;
    float2 wb = tab[lp[i]];
    vout[i] = a*wb.x + wb.y;
  }
  float4 o0 = {vout[0], vout[1], vout[2], vout[3]};
  float4 o1 = {vout[4], vout[5], vout[6], vout[7]};
  *(float4*)yp = o0;
  *(float4*)(yp + 4) = o1;
}

extern "C" void kernel_launch(void* const* d_in, const int* in_sizes, int n_in,
                              void* d_out, int out_size, void* d_ws, size_t ws_size,
                              hipStream_t stream) {
  (void)in_sizes; (void)n_in; (void)out_size; (void)ws_size;
  const void* input       = d_in[0];
  const void* style       = d_in[1];
  const void* class_style = d_in[2];
  const void* weight      = d_in[3];
  const void* mod_w       = d_in[4];
  const void* mod_b       = d_in[5];
  const void* cw_w        = d_in[6];
  const void* cw_b        = d_in[7];
  const void* cb_w        = d_in[8];
  const void* cb_b        = d_in[9];
  const int* label        = (const int*)d_in[10];
  float* y = (float*)d_out;                   // f32 conv result in d_out, normalized in place

  char* ws = (char*)d_ws;
  u16*   xT   = (u16*)  (ws + 0);             // 33,554,432 B  [b][h][w][ci] bf16
  u16*   wT   = (u16*)  (ws + 33554432);      //  4,718,592 B  [tap][cout][ci] bf16
  float* wsqT = (float*)(ws + 38273024);      //  1,048,576 B  [cin][cout]
  float* s    = (float*)(ws + 39321600);      //     16,384 B  [b][ci]
  float* cw   = (float*)(ws + 39337984);      //     71,680 B  [ncls][cout]
  float* cb   = (float*)(ws + 39409664);      //     71,680 B
  float* mu   = (float*)(ws + 39481344);      //     16,384 B
  float* istd = (float*)(ws + 39497728);      //     16,384 B
  float* part = (float*)(ws + 39514112);      //    524,288 B  [b][hblk][cout][2]
  int*   flag = (int*)  (ws + 40038400);      //          4 B  (total 40,038,404 B)

  hipLaunchKernelGGL(sniff_kernel, dim3(1), dim3(64), 0, stream, (const u32*)weight, flag);
  hipLaunchKernelGGL(styles_kernel, dim3(78), dim3(256), 0, stream,
                     style, class_style, mod_w, mod_b, cw_w, cw_b, cb_w, cb_b,
                     (const int*)flag, s, cw, cb);
  hipLaunchKernelGGL(wprep_kernel, dim3(512), dim3(256), 0, stream, weight, (const int*)flag, wT, wsqT);
  hipLaunchKernelGGL(xtrans_kernel, dim3(16, 64, 8), dim3(256), 0, stream, input, s, (const int*)flag, xT);
  hipLaunchKernelGGL(conv_kernel, dim3(8, 16, 8), dim3(256), 0, stream, xT, wT, y, part);
  hipLaunchKernelGGL(finalize_kernel, dim3(16), dim3(256), 0, stream, part, s, wsqT, mu, istd);
  hipLaunchKernelGGL(epi_kernel, dim3(8192), dim3(256), 0, stream, y, mu, istd, cw, cb, label);
}

// Round 7
// 358.603 us; speedup vs baseline: 1.2758x; 1.1097x over previous
//
#include <hip/hip_runtime.h>

typedef unsigned short u16;
typedef unsigned int u32;
typedef __attribute__((ext_vector_type(8))) short short8;
typedef __attribute__((ext_vector_type(4))) float floatx4;

__device__ inline float bf2f(u16 h) {
  union { u32 u; float f; } v; v.u = ((u32)h) << 16; return v.f;
}
__device__ inline u16 f2bf(float f) {
  union { float f; u32 u; } v; v.f = f;
  u32 u = v.u;
  return (u16)((u + 0x7fffu + ((u >> 16) & 1u)) >> 16);
}
// dtype-generic load: isbf is wave-uniform (from sniffer flag)
__device__ inline float ldf(const void* p, int i, int isbf) {
  return isbf ? bf2f(((const u16*)p)[i]) : ((const float*)p)[i];
}

// ---------------- K0: input dtype sniffer ----------------
__global__ void sniff_kernel(const u32* __restrict__ w, int* __restrict__ flag) {
  __shared__ int cnt;
  if (threadIdx.x == 0) cnt = 0;
  __syncthreads();
  int c = 0;
  #pragma unroll
  for (int i = 0; i < 4; ++i) {
    u32 v = w[1024 + threadIdx.x * 4 + i];
    int e = (v >> 7) & 0xFF;          // exponent field of the low u16 as bf16
    if (e >= 96 && e <= 160) c++;
  }
  atomicAdd(&cnt, c);
  __syncthreads();
  if (threadIdx.x == 0) *flag = (cnt >= 154) ? 1 : 0;   // 60% of 256
}

// ---------------- K1: style linears (s[8,512], cw[35,512], cb[35,512]) ----------------
__global__ void styles_kernel(const void* __restrict__ style, const void* __restrict__ class_style,
                              const void* __restrict__ mod_w, const void* __restrict__ mod_b,
                              const void* __restrict__ cw_w, const void* __restrict__ cw_b,
                              const void* __restrict__ cb_w, const void* __restrict__ cb_b,
                              const int* __restrict__ flagp,
                              float* __restrict__ s, float* __restrict__ cw, float* __restrict__ cb) {
  const int isbf = *flagp;
  int row = blockIdx.x;  // 0..77
  const void *vec, *wm, *bias; float* out; int voff;
  if (row < 8)        { vec = style;       voff = row*512;        wm = mod_w; bias = mod_b; out = s  + row*512; }
  else if (row < 43)  { vec = class_style; voff = (row-8)*512;    wm = cw_w;  bias = cw_b;  out = cw + (row-8)*512; }
  else                { vec = class_style; voff = (row-43)*512;   wm = cb_w;  bias = cb_b;  out = cb + (row-43)*512; }
  __shared__ float v[512];
  for (int i = threadIdx.x; i < 512; i += 256) v[i] = ldf(vec, voff + i, isbf);
  __syncthreads();
  const float inv = 0.04419417382415922f;  // 1/sqrt(512)
  for (int o = threadIdx.x; o < 512; o += 256) {
    float acc = 0.f;
    if (isbf) {
      for (int k = 0; k < 512; ++k) acc += bf2f(((const u16*)wm)[o*512 + k]) * v[k];
    } else {
      const float4* wr = (const float4*)((const float*)wm + o*512);
      for (int k = 0; k < 128; ++k) {
        float4 p = wr[k];
        acc += p.x*v[k*4+0] + p.y*v[k*4+1] + p.z*v[k*4+2] + p.w*v[k*4+3];
      }
    }
    out[o] = acc * inv + ldf(bias, o, isbf);
  }
}

// ---------------- K2: weight prep: wT[ck][tap][cout][ci32] + wsqT[cin][cout] ----------------
__global__ void wprep_kernel(const void* __restrict__ weight, const int* __restrict__ flagp,
                             u16* __restrict__ wT, float* __restrict__ wsqT) {
  const int isbf = *flagp;
  const int co = blockIdx.x;
  __shared__ float wsmem[4608];
  for (int i = threadIdx.x; i < 4608; i += 256)
    wsmem[i] = ldf(weight, co*4608 + i, isbf);   // coalesced
  __syncthreads();
  for (int ci = threadIdx.x; ci < 512; ci += 256) {
    float sq = 0.f;
    const int ck = ci >> 5, cin = ci & 31;
    #pragma unroll
    for (int tap = 0; tap < 9; ++tap) {
      float fv = wsmem[ci*9 + tap];
      sq += fv*fv;
      wT[(size_t)(((ck*9 + tap)*512) + co)*32 + cin] = f2bf(fv);
    }
    wsqT[ci*512 + co] = sq;
  }
}

// ---------------- K3: x transpose+modulate: xT[b][ck][h][w][ci32] ----------------
__global__ void xtrans_kernel(const void* __restrict__ x, const float* __restrict__ s,
                              const int* __restrict__ flagp, u16* __restrict__ xT) {
  const int isbf = *flagp;
  const int t = threadIdx.x;
  const int w = t & 63, cq = t >> 6;
  const int b = blockIdx.z, h = blockIdx.y;
  const int ck = blockIdx.x;                 // ci chunk of 32
  const int ci0 = ck*32 + cq*8;
  float f[8];
  #pragma unroll
  for (int j = 0; j < 8; ++j) {
    float xv = ldf(x, (((b*512) + ci0 + j)*64 + h)*64 + w, isbf);
    f[j] = xv * s[b*512 + ci0 + j];
  }
  u32 outp[4];
  #pragma unroll
  for (int i = 0; i < 4; ++i)
    outp[i] = (u32)f2bf(f[2*i]) | ((u32)f2bf(f[2*i+1]) << 16);
  uint4 po = {outp[0], outp[1], outp[2], outp[3]};
  // 4 cq-quarters of a wave fill one full 64B (w,ck) line -> L2 write-combine
  *(uint4*)&xT[(size_t)((((b*16 + ck)*64 + h)*64 + w)*32) + cq*8] = po;
}

// ---------------- K4: MFMA conv + fused IN partial sums ----------------
// Per wave: 64 couts x (2 h x 64 w) via 4m x 8n 16x16x32 frags (0.375 ds_reads/MFMA).
// Block: 64 couts x 8 h x 64 w, 4 waves. Grid (hb 8, b 8, coutblk 8) = 512 = 2/CU.
// LDS: xs [q4][dr10][c66] 16B cells (42240 B) + wsm [tap9][q4][co^] (36864 B) = 79104 B.
__global__ __launch_bounds__(256, 2) void conv_kernel(const u16* __restrict__ xT, const u16* __restrict__ wT,
                                                      float* __restrict__ y, float* __restrict__ part) {
  __shared__ __align__(16) u16 xs[4*10*66*8];
  __shared__ __align__(16) u16 wsm[9*4*64*8];
  const int tid = threadIdx.x;
  const int lane = tid & 63;
  const int wid = tid >> 6;
  const int hb = blockIdx.x, b = blockIdx.y;
  const int ct0 = blockIdx.z * 64;
  const int h0 = hb * 8;

  // zero column-halo cells (c==0, c==65) for all q 0..3, dr 0..9 (80 cells)
  if (tid < 80) {
    int q = tid / 20, rem = tid % 20, dr = rem >> 1, side = rem & 1;
    uint4 z = {0,0,0,0};
    *(uint4*)&xs[(((q*10 + dr)*66) + side*65)*8] = z;
  }

  floatx4 acc[4][8];
  #pragma unroll
  for (int i = 0; i < 4; ++i) {
    #pragma unroll
    for (int j = 0; j < 8; ++j) acc[i][j] = (floatx4)(0.f);
  }

  const int m = lane & 15, qd = lane >> 4;

  for (int ck = 0; ck < 16; ++ck) {
    __syncthreads();  // prev chunk's MFMA reads done (and halo zeros, 1st iter)

    // stage x: 2560 16B cells, 10/thread; global reads fully contiguous 1KB/wave
    #pragma unroll
    for (int j = 0; j < 10; ++j) {
      int g = tid + j*256;                    // 0..2559
      int q = g & 3, c64 = (g >> 2) & 63, dr = g >> 8;
      int hin = h0 + dr - 1;
      uint4 v = {0,0,0,0};
      if (hin >= 0 && hin <= 63)
        v = *(const uint4*)&xT[(size_t)((((b*16 + ck)*64 + hin)*64 + c64)*32) + q*8];
      *(uint4*)&xs[(((q*10 + dr)*66) + 1 + c64)*8] = v;
    }
    // stage w: 2304 16B cells, 9/thread; contiguous 1KB/wave
    #pragma unroll
    for (int j = 0; j < 9; ++j) {
      int g = tid + j*256;                    // 0..2303
      int q = g & 3, co = (g >> 2) & 63, tap = g >> 8;
      uint4 v = *(const uint4*)&wT[(size_t)(((ck*9 + tap)*512) + ct0 + co)*32 + q*8];
      *(uint4*)&wsm[(((tap*4 + q)*64) + (co ^ (q << 2)))*8] = v;
    }
    __syncthreads();

    #pragma unroll
    for (int tap = 0; tap < 9; ++tap) {
      const int k1 = tap / 3, k2 = tap - k1*3;
      short8 af[4], bfr[8];
      #pragma unroll
      for (int mi = 0; mi < 4; ++mi)
        af[mi] = *(const short8*)&wsm[(((tap*4 + qd)*64) + ((mi*16 + m) ^ (qd << 2)))*8];
      #pragma unroll
      for (int hh = 0; hh < 2; ++hh) {
        const int dr = wid*2 + hh + k1;       // 0..9
        #pragma unroll
        for (int nw = 0; nw < 4; ++nw)
          bfr[hh*4 + nw] = *(const short8*)&xs[(((qd*10 + dr)*66) + nw*16 + m + k2)*8];
      }
      #pragma unroll
      for (int ni = 0; ni < 8; ++ni) {
        #pragma unroll
        for (int mi = 0; mi < 4; ++mi)
          acc[mi][ni] = __builtin_amdgcn_mfma_f32_16x16x32_bf16(af[mi], bfr[ni], acc[mi][ni], 0, 0, 0);
      }
    }
  }

  // write y (pre-norm conv result, f32) into d_out
  #pragma unroll
  for (int mi = 0; mi < 4; ++mi) {
    #pragma unroll
    for (int hh = 0; hh < 2; ++hh) {
      const int h = h0 + wid*2 + hh;
      #pragma unroll
      for (int nw = 0; nw < 4; ++nw) {
        #pragma unroll
        for (int r = 0; r < 4; ++r) {
          int co = ct0 + mi*16 + qd*4 + r;    // C/D: row=(lane>>4)*4+reg, col=lane&15
          int w = nw*16 + m;
          y[(size_t)(((b*512) + co)*64 + h)*64 + w] = acc[mi][hh*4 + nw][r];
        }
      }
    }
  }

  // fused IN partials: per-cout sum / sumsq over this block's 8x64 tile
  float s1[16], s2[16];
  #pragma unroll
  for (int mi = 0; mi < 4; ++mi) {
    #pragma unroll
    for (int r = 0; r < 4; ++r) {
      float a = 0.f, aa = 0.f;
      #pragma unroll
      for (int ni = 0; ni < 8; ++ni) {
        float v = acc[mi][ni][r];
        a += v; aa += v*v;
      }
      s1[mi*4+r] = a; s2[mi*4+r] = aa;
    }
  }
  #pragma unroll
  for (int off = 1; off < 16; off <<= 1) {
    #pragma unroll
    for (int i = 0; i < 16; ++i) {
      s1[i] += __shfl_xor(s1[i], off, 64);
      s2[i] += __shfl_xor(s2[i], off, 64);
    }
  }
  __syncthreads();                 // all waves done reading xs for MFMA
  float* red = (float*)xs;         // reuse LDS: [wid][co][2] = 512 floats
  if (m == 0) {
    #pragma unroll
    for (int mi = 0; mi < 4; ++mi) {
      #pragma unroll
      for (int r = 0; r < 4; ++r) {
        int co = mi*16 + qd*4 + r;
        red[(wid*64 + co)*2 + 0] = s1[mi*4+r];
        red[(wid*64 + co)*2 + 1] = s2[mi*4+r];
      }
    }
  }
  __syncthreads();
  if (tid < 128) {
    int co = tid >> 1, which = tid & 1;
    float v = (red[(0*64+co)*2+which] + red[(1*64+co)*2+which])
            + (red[(2*64+co)*2+which] + red[(3*64+co)*2+which]);
    part[(size_t)(((b*8 + hb)*512) + ct0 + co)*2 + which] = v;
  }
}

// ---------------- K5: finalize mu/istd from partials + SS-eps term ----------------
__global__ void finalize_kernel(const float* __restrict__ part, const float* __restrict__ s,
                                const float* __restrict__ wsqT,
                                float* __restrict__ mu, float* __restrict__ istd) {
  const int gid = blockIdx.x*256 + threadIdx.x;   // 0..4095 = b*512+co
  const int b = gid >> 9, co = gid & 511;
  float S = 0.f, Q = 0.f;
  #pragma unroll
  for (int hb = 0; hb < 8; ++hb) {
    S += part[(size_t)(((b*8 + hb)*512) + co)*2 + 0];
    Q += part[(size_t)(((b*8 + hb)*512) + co)*2 + 1];
  }
  float SS = 0.f;
  for (int ci = 0; ci < 512; ++ci) {
    float sv = s[b*512 + ci];
    SS += sv*sv * wsqT[ci*512 + co];   // coalesced across threads
  }
  float mval = S * (1.f/4096.f);
  float var = fmaxf(Q * (1.f/4096.f) - mval*mval, 0.f);
  float eps = 1e-5f*SS + 4.608e-10f;   // = eps_in/(scale*demod)^2, exact
  mu[gid] = mval;
  istd[gid] = rsqrtf(var + eps);
}

// ---------------- K6: normalize + CLADE (in place on d_out, f32) ----------------
__global__ void epi_kernel(float* __restrict__ y, const float* __restrict__ mu, const float* __restrict__ istd,
                           const float* __restrict__ cw, const float* __restrict__ cb,
                           const int* __restrict__ label) {
  __shared__ float2 tab[35];
  const int blk = blockIdx.x;          // 8192 = 4096 planes x 2 halves
  const int bc = blk >> 1, half = blk & 1;
  const int b = bc >> 9, co = bc & 511;
  const int t = threadIdx.x;
  if (t < 35) tab[t] = make_float2(cw[t*512 + co], cb[t*512 + co]);
  __syncthreads();
  const float mval = mu[bc], is = istd[bc];
  const int base = half*2048 + t*8;
  const int h = base >> 6, w = base & 63;
  float* yp = y + (size_t)bc*4096 + base;
  float4 v0 = *(const float4*)yp;
  float4 v1 = *(const float4*)(yp + 4);
  const int* lp = label + ((b*64) + h)*64 + w;
  float vin[8] = {v0.x, v0.y, v0.z, v0.w, v1.x, v1.y, v1.z, v1.w};
  float vout[8];
  #pragma unroll
  for (int i = 0; i < 8; ++i) {
    float a = (vin[i] - mval) * is;
    float2 wb = tab[lp[i]];
    vout[i] = a*wb.x + wb.y;
  }
  float4 o0 = {vout[0], vout[1], vout[2], vout[3]};
  float4 o1 = {vout[4], vout[5], vout[6], vout[7]};
  *(float4*)yp = o0;
  *(float4*)(yp + 4) = o1;
}

extern "C" void kernel_launch(void* const* d_in, const int* in_sizes, int n_in,
                              void* d_out, int out_size, void* d_ws, size_t ws_size,
                              hipStream_t stream) {
  (void)in_sizes; (void)n_in; (void)out_size; (void)ws_size;
  const void* input       = d_in[0];
  const void* style       = d_in[1];
  const void* class_style = d_in[2];
  const void* weight      = d_in[3];
  const void* mod_w       = d_in[4];
  const void* mod_b       = d_in[5];
  const void* cw_w        = d_in[6];
  const void* cw_b        = d_in[7];
  const void* cb_w        = d_in[8];
  const void* cb_b        = d_in[9];
  const int* label        = (const int*)d_in[10];
  float* y = (float*)d_out;                   // f32 conv result in d_out, normalized in place

  char* ws = (char*)d_ws;
  u16*   xT   = (u16*)  (ws + 0);             // 33,554,432 B  [b][ck16][h][w][ci32] bf16
  u16*   wT   = (u16*)  (ws + 33554432);      //  4,718,592 B  [ck16][tap][cout][ci32] bf16
  float* wsqT = (float*)(ws + 38273024);      //  1,048,576 B  [cin][cout]
  float* s    = (float*)(ws + 39321600);      //     16,384 B  [b][ci]
  float* cw   = (float*)(ws + 39337984);      //     71,680 B  [ncls][cout]
  float* cb   = (float*)(ws + 39409664);      //     71,680 B
  float* mu   = (float*)(ws + 39481344);      //     16,384 B
  float* istd = (float*)(ws + 39497728);      //     16,384 B
  float* part = (float*)(ws + 39514112);      //    262,144 B  [b][hb8][cout][2]
  int*   flag = (int*)  (ws + 39776256);      //          4 B  (total 39,776,260 B)

  hipLaunchKernelGGL(sniff_kernel, dim3(1), dim3(64), 0, stream, (const u32*)weight, flag);
  hipLaunchKernelGGL(styles_kernel, dim3(78), dim3(256), 0, stream,
                     style, class_style, mod_w, mod_b, cw_w, cw_b, cb_w, cb_b,
                     (const int*)flag, s, cw, cb);
  hipLaunchKernelGGL(wprep_kernel, dim3(512), dim3(256), 0, stream, weight, (const int*)flag, wT, wsqT);
  hipLaunchKernelGGL(xtrans_kernel, dim3(16, 64, 8), dim3(256), 0, stream, input, s, (const int*)flag, xT);
  hipLaunchKernelGGL(conv_kernel, dim3(8, 8, 8), dim3(256), 0, stream, xT, wT, y, part);
  hipLaunchKernelGGL(finalize_kernel, dim3(16), dim3(256), 0, stream, part, s, wsqT, mu, istd);
  hipLaunchKernelGGL(epi_kernel, dim3(8192), dim3(256), 0, stream, y, mu, istd, cw, cb, label);
}